// Round 11
// baseline (345.195 us; speedup 1.0000x reference)
//
#include <hip/hip_runtime.h>

// MHA forward.  B=4 T=2048 DM=1024 H=16 DK=DV=64.  f32 in / f32 out.
// R11: proj + attn staging via __builtin_amdgcn_global_load_lds (16B DMA,
//      m97 pattern, unpadded lane-contiguous LDS tiles).  attn: 64-row
//      q-tiles paired (qt,31-qt), 128-col s-tiles (half the barriers and
//      shuffle reductions), LDS exactly 40KB -> 4 blocks/CU, exp2-domain
//      softmax (Q pre-scaled by 0.125*log2e at proj).

#define B_  4
#define T_  2048
#define DM_ 1024
#define H_  16
#define D_  64
#define DMO 1024   // out row stride = H_*D_

typedef unsigned short u16;
typedef unsigned int   u32;
typedef u16   u16x8 __attribute__((ext_vector_type(8)));
typedef short s16x8 __attribute__((ext_vector_type(8)));
typedef float f32x4 __attribute__((ext_vector_type(4)));
typedef u32   u32x4 __attribute__((ext_vector_type(4)));

__device__ __forceinline__ u16 f2bf_hu(float f) {   // round-half-up
    u32 u = __builtin_bit_cast(u32, f) + 0x8000u;
    return (u16)(u >> 16);
}
__device__ __forceinline__ u32 pk2(float lo, float hi) {
    u32 ul = __builtin_bit_cast(u32, lo) + 0x8000u;
    u32 uh = __builtin_bit_cast(u32, hi) + 0x8000u;
    return __builtin_amdgcn_perm(uh, ul, 0x07060302);
}
__device__ __forceinline__ u16x8 cvt8(const float* s) {
    f32x4 a = *(const f32x4*)s;
    f32x4 b = *(const f32x4*)(s + 4);
    u32x4 r { pk2(a[0], a[1]), pk2(a[2], a[3]), pk2(b[0], b[1]), pk2(b[2], b[3]) };
    return __builtin_bit_cast(u16x8, r);
}
__device__ __forceinline__ f32x4 mfma16(u16x8 a, u16x8 b, f32x4 c) {
    return __builtin_amdgcn_mfma_f32_16x16x32_bf16(
        __builtin_bit_cast(s16x8, a), __builtin_bit_cast(s16x8, b), c, 0, 0, 0);
}
__device__ __forceinline__ void glds16(const u16* g, u16* l) {
    __builtin_amdgcn_global_load_lds(
        (const __attribute__((address_space(1))) void*)g,
        (__attribute__((address_space(3))) void*)l, 16, 0, 0);
}
__device__ __forceinline__ float fexp2(float x) {
#if __has_builtin(__builtin_amdgcn_exp2f)
    return __builtin_amdgcn_exp2f(x);
#else
    return __expf(x * 0.69314718056f);
#endif
}

// ---------------------------------------------------------------------------
// cvt_x: x f32 [8192][1024] -> xb bf16 (same layout).
// ---------------------------------------------------------------------------
__global__ __launch_bounds__(256) void cvt_x(const float* __restrict__ x,
                                             u16* __restrict__ xb) {
    size_t i0 = ((size_t)blockIdx.x * 256 + threadIdx.x) * 32;
    #pragma unroll
    for (int c = 0; c < 4; c++)
        *(u16x8*)(xb + i0 + c * 8) = cvt8(x + i0 + c * 8);
}

// ---------------------------------------------------------------------------
// cvt_w: W[mat][h][d][dk] f32 -> Wt[(mat*16+h)*64+dk][d] bf16 (transposed).
// ---------------------------------------------------------------------------
__global__ __launch_bounds__(256) void cvt_w(
    const float* __restrict__ Wq, const float* __restrict__ Wk,
    const float* __restrict__ Wv, u16* __restrict__ Wt) {
    __shared__ u16 L[64][74];
    const int dblk = blockIdx.x, h = blockIdx.y, mat = blockIdx.z;
    const float* W = (mat == 0) ? Wq : (mat == 1) ? Wk : Wv;
    const int tid = threadIdx.x;
    {
        const int dl = tid >> 2, c = (tid & 3) * 16;
        const float* src = W + ((size_t)h * DM_ + dblk * 64 + dl) * D_ + c;
        #pragma unroll
        for (int g = 0; g < 2; g++)
            *(u16x8*)&L[dl][c + g * 8] = cvt8(src + g * 8);
    }
    __syncthreads();
    {
        const int dkr = tid >> 2, g = tid & 3;
        u16 tmp[16];
        #pragma unroll
        for (int j = 0; j < 16; j++) tmp[j] = L[g * 16 + j][dkr];
        u16* dst = Wt + ((size_t)(mat * 16 + h) * 64 + dkr) * DM_ + dblk * 64 + g * 16;
        *(u16x8*)dst = *(u16x8*)tmp;
        *(u16x8*)(dst + 8) = *(u16x8*)(tmp + 8);
    }
}

// ---------------------------------------------------------------------------
// Projection GEMM (m97-style): C[8192][3072] = xb @ Wt^T.
// grid (64,24), 256 thr = 4 waves 2x2, 128x128 tile, BK=64, DMA staging
// into unpadded LDS.  Q scaled by 0.125*log2e; V stored transposed.
// ---------------------------------------------------------------------------
__global__ __launch_bounds__(256) void proj_kernel(
    const u16* __restrict__ xb, const u16* __restrict__ Wt,
    u16* __restrict__ Qc, u16* __restrict__ Kc, u16* __restrict__ Vtc)
{
    __shared__ u16 As[128][64];   // unpadded: lane-contiguous DMA dest
    __shared__ u16 Bs[128][64];

    const int m0 = blockIdx.x * 128;
    const int n0 = blockIdx.y * 128;
    const int mat = n0 >> 10;
    const int tid  = threadIdx.x;
    const int wave = tid >> 6, lane = tid & 63;
    const int quad = lane >> 4, l16 = lane & 15;
    const int wm   = wave >> 1, wn = wave & 1;

    f32x4 acc[4][4];
    #pragma unroll
    for (int i = 0; i < 4; i++)
        #pragma unroll
        for (int j = 0; j < 4; j++) acc[i][j] = f32x4{0.f, 0.f, 0.f, 0.f};

    for (int kb = 0; kb < 16; kb++) {
        const int kbase = kb * 64;
        __syncthreads();
        #pragma unroll
        for (int l = 0; l < 4; l++) {
            const int c   = l * 256 + tid;       // chunk 0..1023
            const int row = c >> 3, kc = (c & 7) * 8;
            glds16(xb + (size_t)(m0 + row) * DM_ + kbase + kc, &As[row][kc]);
            glds16(Wt + (size_t)(n0 + row) * DM_ + kbase + kc, &Bs[row][kc]);
        }
        __syncthreads();
        #pragma unroll
        for (int ks = 0; ks < 2; ks++) {
            u16x8 af[4], bf[4];
            #pragma unroll
            for (int i = 0; i < 4; i++)
                af[i] = *(const u16x8*)&As[wm * 64 + i * 16 + l16][ks * 32 + quad * 8];
            #pragma unroll
            for (int j = 0; j < 4; j++)
                bf[j] = *(const u16x8*)&Bs[wn * 64 + j * 16 + l16][ks * 32 + quad * 8];
            #pragma unroll
            for (int i = 0; i < 4; i++)
                #pragma unroll
                for (int j = 0; j < 4; j++)
                    acc[i][j] = mfma16(af[i], bf[j], acc[i][j]);
        }
    }

    // epilogue: C/D row = quad*4+r, col = l16 (m89)
    #pragma unroll
    for (int i = 0; i < 4; i++) {
        #pragma unroll
        for (int j = 0; j < 4; j++) {
            #pragma unroll
            for (int r = 0; r < 4; r++) {
                const int m  = m0 + wm * 64 + i * 16 + quad * 4 + r;
                const int bb = m >> 11, t = m & (T_ - 1);
                const int nloc = wn * 64 + j * 16 + l16;
                const int h  = ((n0 & 1023) >> 6) + (nloc >> 6);
                const int dk = nloc & 63;
                float v = acc[i][j][r];
                if (mat == 0) {   // Q scaled by dk^-0.5 * log2(e) for exp2 softmax
                    Qc[((size_t)(bb * H_ + h) * T_ + t) * D_ + dk] =
                        f2bf_hu(v * 0.18033688f);
                } else if (mat == 1) {
                    Kc[((size_t)(bb * H_ + h) * T_ + t) * D_ + dk] = f2bf_hu(v);
                } else {
                    Vtc[((size_t)(bb * H_ + h) * D_ + dk) * T_ + t] = f2bf_hu(v);
                }
            }
        }
    }
}

// ---------------------------------------------------------------------------
// Flash attention: grid (16 pairs, 16 heads, 4 batch) x 256.
// Block handles 64-row q-tiles {bx, 31-bx} -> exactly 17 128-col s-tiles
// per block.  Wave owns 16 q-rows.  LDS = 16+16+8 = 40KB -> 4 blocks/CU.
// ---------------------------------------------------------------------------
__global__ __launch_bounds__(256, 4) void attn_kernel(
    const u16* __restrict__ Qc, const u16* __restrict__ Kc,
    const u16* __restrict__ Vtc, float* __restrict__ out)
{
    __shared__ u16 Ks[128][64];    // [s_local][dk]   unpadded (DMA dest)
    __shared__ u16 Vs[64][128];    // [dv][s_local]   unpadded (DMA dest)
    __shared__ u16 Ps[4][16][64];  // per-wave P half-tile

    const int h = blockIdx.y, b = blockIdx.z;
    const int tid = threadIdx.x, wave = tid >> 6, lane = tid & 63;
    const int quad = lane >> 4, l16 = lane & 15;

    const u16* Qbh = Qc + (size_t)(b * H_ + h) * T_ * D_;
    const u16* Kbh = Kc + (size_t)(b * H_ + h) * T_ * D_;
    const u16* Vbh = Vtc + (size_t)(b * H_ + h) * D_ * T_;

    for (int ph = 0; ph < 2; ph++) {
        const int qt = ph ? (31 - blockIdx.x) : blockIdx.x;
        const int q0 = qt * 64;

        // Q fragments (pre-scaled at projection)
        u16x8 qf[2];
        {
            const int qrow = q0 + wave * 16 + l16;
            #pragma unroll
            for (int ks = 0; ks < 2; ks++)
                qf[ks] = *(const u16x8*)(Qbh + (size_t)qrow * D_ + ks * 32 + quad * 8);
        }

        f32x4 o[4];
        float mi[4], li[4];
        #pragma unroll
        for (int i = 0; i < 4; i++) {
            o[i] = f32x4{0.f, 0.f, 0.f, 0.f};
            mi[i] = -1e30f; li[i] = 0.f;
        }

        const int nst = (qt >> 1) + 1;
        for (int st = 0; st < nst; st++) {
            const int s0 = st * 128;
            __syncthreads();
            // DMA-stage K (128x64) and V^T (64x128)
            #pragma unroll
            for (int l = 0; l < 4; l++) {
                const int c = l * 256 + tid;
                glds16(Kbh + (size_t)(s0 + (c >> 3)) * D_ + (c & 7) * 8,
                       &Ks[c >> 3][(c & 7) * 8]);
                glds16(Vbh + (size_t)(c >> 4) * T_ + s0 + (c & 15) * 8,
                       &Vs[c >> 4][(c & 15) * 8]);
            }
            __syncthreads();

            // S = Q K^T  (8 col-frags = 128 cols)
            f32x4 s[8];
            #pragma unroll
            for (int i = 0; i < 8; i++) s[i] = f32x4{0.f, 0.f, 0.f, 0.f};
            #pragma unroll
            for (int ks = 0; ks < 2; ks++)
                #pragma unroll
                for (int nt = 0; nt < 8; nt++) {
                    u16x8 bfr = *(const u16x8*)&Ks[nt * 16 + l16][ks * 32 + quad * 8];
                    s[nt] = mfma16(qf[ks], bfr, s[nt]);
                }

            // causal mask — only the last s-tile can cross the diagonal
            if (st == nst - 1) {
                #pragma unroll
                for (int nt = 0; nt < 8; nt++) {
                    const int sc = s0 + nt * 16 + l16;
                    #pragma unroll
                    for (int r = 0; r < 4; r++) {
                        const int qr = q0 + wave * 16 + quad * 4 + r;
                        if (sc > qr) s[nt][r] = -1e30f;
                    }
                }
            }

            // online softmax (log2 domain), row = quad*4+r
            #pragma unroll
            for (int r = 0; r < 4; r++) {
                float mx = s[0][r];
                #pragma unroll
                for (int nt = 1; nt < 8; nt++) mx = fmaxf(mx, s[nt][r]);
                #pragma unroll
                for (int off = 1; off < 16; off <<= 1)
                    mx = fmaxf(mx, __shfl_xor(mx, off));
                const float mn = fmaxf(mi[r], mx);
                const float alpha = fexp2(mi[r] - mn);
                float sum = 0.f;
                #pragma unroll
                for (int nt = 0; nt < 8; nt++) {
                    const float p = fexp2(s[nt][r] - mn);
                    s[nt][r] = p;
                    sum += p;
                }
                #pragma unroll
                for (int off = 1; off < 16; off <<= 1)
                    sum += __shfl_xor(sum, off);
                li[r] = li[r] * alpha + sum;
                mi[r] = mn;
                #pragma unroll
                for (int nt = 0; nt < 4; nt++) o[nt][r] *= alpha;
            }

            // O += P V in two 64-col halves (Ps wave-private: no barrier)
            #pragma unroll
            for (int hf = 0; hf < 2; hf++) {
                #pragma unroll
                for (int nt = 0; nt < 4; nt++)
                    #pragma unroll
                    for (int r = 0; r < 4; r++)
                        Ps[wave][quad * 4 + r][nt * 16 + l16] =
                            f2bf_hu(s[hf * 4 + nt][r]);
                #pragma unroll
                for (int ks = 0; ks < 2; ks++) {
                    u16x8 a = *(const u16x8*)&Ps[wave][l16][ks * 32 + quad * 8];
                    #pragma unroll
                    for (int nt = 0; nt < 4; nt++) {
                        u16x8 bv = *(const u16x8*)
                            &Vs[nt * 16 + l16][hf * 64 + ks * 32 + quad * 8];
                        o[nt] = mfma16(a, bv, o[nt]);
                    }
                }
            }
        }

        // f32 output
        float inv[4];
        #pragma unroll
        for (int r = 0; r < 4; r++) inv[r] = 1.f / li[r];
        #pragma unroll
        for (int nt = 0; nt < 4; nt++)
            #pragma unroll
            for (int r = 0; r < 4; r++) {
                const int qr = q0 + wave * 16 + quad * 4 + r;
                out[(size_t)(b * T_ + qr) * DMO + h * D_ + nt * 16 + l16] =
                    o[nt][r] * inv[r];
            }
    }
}

// ---------------------------------------------------------------------------
extern "C" void kernel_launch(void* const* d_in, const int* in_sizes, int n_in,
                              void* d_out, int out_size, void* d_ws, size_t ws_size,
                              hipStream_t stream) {
    int xi = 0, wi[3] = {1, 2, 3};
    {
        int k = 0, found = 0;
        for (int i = 0; i < n_in && i < 8; i++) {
            if (in_sizes[i] == B_ * T_ * DM_) { xi = i; found = 1; }
            else if (in_sizes[i] == H_ * DM_ * D_ && k < 3) wi[k++] = i;
        }
        if (!found || k != 3) { xi = 0; wi[0] = 1; wi[1] = 2; wi[2] = 3; }
    }
    const float* x  = (const float*)d_in[xi];
    const float* Wq = (const float*)d_in[wi[0]];
    const float* Wk = (const float*)d_in[wi[1]];
    const float* Wv = (const float*)d_in[wi[2]];
    float* out = (float*)d_out;

    // bf16 staging scratch in d_out (dead before attn writes out)
    u16* xb = (u16*)d_out;
    u16* Wt = xb + (size_t)B_ * T_ * DM_;
    // ws: Q + K + Vt bf16
    const size_t per = (size_t)B_ * H_ * T_ * D_;
    u16* Qc  = (u16*)d_ws;
    u16* Kc  = Qc + per;
    u16* Vtc = Kc + per;

    cvt_x<<<1024, 256, 0, stream>>>(x, xb);
    cvt_w<<<dim3(16, 16, 3), 256, 0, stream>>>(Wq, Wk, Wv, Wt);
    proj_kernel<<<dim3(64, 24), 256, 0, stream>>>(xb, Wt, Qc, Kc, Vtc);
    attn_kernel<<<dim3(16, 16, 4), 256, 0, stream>>>(Qc, Kc, Vtc, out);
}